// Round 3
// baseline (324.601 us; speedup 1.0000x reference)
//
#include <hip/hip_runtime.h>
#include <hip/hip_bf16.h>

typedef __attribute__((ext_vector_type(8))) short short8;
typedef __attribute__((ext_vector_type(4))) float f32x4;

union U16x8 { uint4 u; short8 s; unsigned short us[8]; };

#define S_LEN 4096
#define DH    128
#define TQ    16          // queries per block
#define VTS   168         // V^T LDS row stride in u16 (21 groups of 8, 336B rows)
#define PST   168         // P LDS row stride in u16
#define XSTR  136         // x-tile LDS stride (bf16 elems)
#define NBLK  512

// ---- device-scope sense-reversing grid barrier ----------------------------
// Safe: grid=512, LDS 49KB (3 blk/CU) and __launch_bounds__(256,2) (VGPR<=256
// -> >=2 blk/CU) guarantee all 512 blocks co-resident. __threadfence() =
// agent-scope fence -> L2 writeback/invalidate (cross-XCD visibility that
// kernel boundaries used to provide).
__device__ unsigned g_cnt = 0;
__device__ unsigned g_gen = 0;

__device__ __forceinline__ void grid_barrier() {
    __syncthreads();
    __threadfence();                       // release: publish k/v stores
    if (threadIdx.x == 0) {
        unsigned gen = __hip_atomic_load(&g_gen, __ATOMIC_ACQUIRE, __HIP_MEMORY_SCOPE_AGENT);
        unsigned old = __hip_atomic_fetch_add(&g_cnt, 1u, __ATOMIC_ACQ_REL, __HIP_MEMORY_SCOPE_AGENT);
        if (old == NBLK - 1) {
            __hip_atomic_store(&g_cnt, 0u, __ATOMIC_RELAXED, __HIP_MEMORY_SCOPE_AGENT);
            __hip_atomic_fetch_add(&g_gen, 1u, __ATOMIC_ACQ_REL, __HIP_MEMORY_SCOPE_AGENT);
        } else {
            while (__hip_atomic_load(&g_gen, __ATOMIC_ACQUIRE, __HIP_MEMORY_SCOPE_AGENT) == gen)
                __builtin_amdgcn_s_sleep(16);
        }
    }
    __syncthreads();
    __threadfence();                       // acquire: invalidate stale lines
}

// ---- 8x8 u16 in-register transpose (32 v_perm) + swizzled VT write --------
__device__ inline void vt_xpose_write(unsigned short* VT, const uint4* vr,
                                      int kgp, int dgp)
{
    unsigned w[8][4];   // w[dim][key-pair]
    #pragma unroll
    for (int p = 0; p < 4; ++p) {
        #pragma unroll
        for (int j = 0; j < 4; ++j) {
            unsigned xlo = ((const unsigned*)&vr[2*p])[j];     // key 2p,  dims 2j,2j+1
            unsigned ylo = ((const unsigned*)&vr[2*p+1])[j];   // key 2p+1
            w[2*j][p]   = __builtin_amdgcn_perm(ylo, xlo, 0x05040100u);
            w[2*j+1][p] = __builtin_amdgcn_perm(ylo, xlo, 0x07060302u);
        }
    }
    int sw = kgp + (dgp & 7); if (sw >= 21) sw -= 21;   // bank swizzle, rotate mod 21
    #pragma unroll
    for (int d = 0; d < 8; ++d) {
        int row = dgp*8 + d;
        *(uint4*)&VT[row*VTS + sw*8] =
            make_uint4(w[d][0], w[d][1], w[d][2], w[d][3]);
    }
}

// ---------------- Fused QKV + sliding-window attention ---------------------
// Phase 0: stage own 16 x-rows hi/lo in LDS (aliased into VT); convert a
//          96-elem slice of W -> WT bf16 (distributed over the grid).
// Phase 1: q/k/v for own 16 rows via MFMA, WT B-frags contiguous.
// Phase 2: r2 attn body (unchanged math).
__global__ __launch_bounds__(256, 2) void fused_kernel(
    const float* __restrict__ x,
    const float* __restrict__ Wq, const float* __restrict__ bq,
    const float* __restrict__ Wk, const float* __restrict__ bk,
    const float* __restrict__ Wv, const float* __restrict__ bv,
    __hip_bfloat16* __restrict__ qg, __hip_bfloat16* __restrict__ kg,
    __hip_bfloat16* __restrict__ vg, unsigned short* __restrict__ WT,
    float* __restrict__ out, const int* __restrict__ wsz)
{
    __shared__ __align__(16) unsigned short VT[128 * VTS];   // 43 KB
    __shared__ __align__(16) unsigned short Pm[TQ * PST];    // 5.25 KB
    __shared__ float pmax[4][16];
    __shared__ float psum[4][16];

    const int t    = threadIdx.x;
    const int wave = t >> 6, lane = t & 63;
    const int i = lane & 15, g = lane >> 4;
    const int bid  = blockIdx.x;
    const int qblk = (bid & 7) * 64 + (bid >> 3);   // XCD swizzle, 512 blocks
    const int b    = qblk >> 8;
    const int s0   = (qblk & 255) * TQ;
    const int grow0 = b * S_LEN + s0;

    unsigned short* XH = VT;                 // phase-0/1 alias into VT region
    unsigned short* XL = VT + 16 * XSTR;     // 2 x 4.25 KB << 43 KB

    // ---- phase 0a: stage own 16 x rows as hi/lo bf16 ----
    {
        int r = t >> 4, cg = t & 15;         // row, 8-elem group
        const float* xp = x + (size_t)(grow0 + r) * DH + cg * 8;
        float4 va = *(const float4*)xp;
        float4 vb = *(const float4*)(xp + 4);
        float xs[8] = {va.x, va.y, va.z, va.w, vb.x, vb.y, vb.z, vb.w};
        U16x8 h, l;
        #pragma unroll
        for (int j = 0; j < 8; ++j) {
            __hip_bfloat16 hb = __float2bfloat16(xs[j]);
            float hf = __bfloat162float(hb);
            __hip_bfloat16 lb = __float2bfloat16(xs[j] - hf);
            h.us[j] = *(unsigned short*)&hb;
            l.us[j] = *(unsigned short*)&lb;
        }
        *(uint4*)&XH[r * XSTR + cg * 8] = h.u;
        *(uint4*)&XL[r * XSTR + cg * 8] = l.u;
    }

    // ---- phase 0b: distributed W -> WT bf16 (49152 elems / 512 blocks) ----
    if (t < 96) {
        int e = bid * 96 + t;
        int mat = e >> 14, rem = e & 16383;          // rem = kk*128 + col
        int kk = rem >> 7, col = rem & 127;
        const float* W = (mat == 0) ? Wq : (mat == 1) ? Wk : Wv;
        __hip_bfloat16 wb = __float2bfloat16(W[rem]);
        WT[mat * 16384 + col * 128 + kk] = *(unsigned short*)&wb;
    }
    __syncthreads();

    // ---- A-frags for own 16 rows (held in regs through phase 1) ----
    short8 ah[4], al[4];
    #pragma unroll
    for (int kc = 0; kc < 4; ++kc) {
        ah[kc] = *(const short8*)&XH[i * XSTR + kc*32 + g*8];
        al[kc] = *(const short8*)&XL[i * XSTR + kc*32 + g*8];
    }

    grid_barrier();   // WT visible everywhere

    // ---- phase 1: 24 (mat, col-tile) jobs over 4 waves ----
    #pragma unroll
    for (int jj = 0; jj < 6; ++jj) {
        int job = wave * 6 + jj;
        int mat = job >> 3, ct = job & 7;
        const float* bias_p = (mat == 0) ? bq : (mat == 1) ? bk : bv;
        __hip_bfloat16* O = (mat == 0) ? qg : (mat == 1) ? kg : vg;
        int col = ct * 16 + i;
        float bias = bias_p[col];
        const unsigned short* wt = WT + mat * 16384 + col * 128;

        short8 bf[4];
        #pragma unroll
        for (int kc = 0; kc < 4; ++kc)
            bf[kc] = *(const short8*)(wt + kc*32 + g*8);

        f32x4 acc; acc[0]=0.f; acc[1]=0.f; acc[2]=0.f; acc[3]=0.f;
        #pragma unroll
        for (int kc = 0; kc < 4; ++kc) {
            acc = __builtin_amdgcn_mfma_f32_16x16x32_bf16(ah[kc], bf[kc], acc, 0, 0, 0);
            acc = __builtin_amdgcn_mfma_f32_16x16x32_bf16(al[kc], bf[kc], acc, 0, 0, 0);
        }
        #pragma unroll
        for (int r = 0; r < 4; ++r) {
            O[(size_t)(grow0 + g*4 + r) * DH + col] = __float2bfloat16(acc[r] + bias);
        }
    }

    grid_barrier();   // q/k/v visible everywhere

    // =================== phase 2: attention (r2 body) ======================
    const int k0   = s0 - 64;
    const int half = wsz[0] >> 1;
    const float scale = 0.08838834764831845f;

    const __hip_bfloat16* kb = kg + (size_t)b * S_LEN * DH;
    const __hip_bfloat16* vb = vg + (size_t)b * S_LEN * DH;

    // ---- V tile loads (issued first; 8 keys x 8 dims per tile) ----
    const int kgp0 = t >> 4, dgp0 = t & 15;          // tile t
    const bool two = (t & 3) == 0;
    const int tau2 = 256 + (t >> 2);                 // tiles 256..319
    const int kgp1 = tau2 >> 4, dgp1 = tau2 & 15;
    uint4 vr0[8], vr1[8];
    #pragma unroll
    for (int r = 0; r < 8; ++r) {
        int key = k0 + kgp0*8 + r;
        uint4 val = make_uint4(0u,0u,0u,0u);
        if (key >= 0 && key < S_LEN)
            val = *(const uint4*)(vb + (size_t)key * DH + dgp0*8);
        vr0[r] = val;
    }
    #pragma unroll
    for (int r = 0; r < 8; ++r) {
        int key = k0 + kgp1*8 + r;
        uint4 val = make_uint4(0u,0u,0u,0u);
        if (two && key >= 0 && key < S_LEN)
            val = *(const uint4*)(vb + (size_t)key * DH + dgp1*8);
        vr1[r] = val;
    }

    // ---- Q A-frags from global (same rows for all 4 waves -> cached) ----
    short8 aq[4];
    {
        const __hip_bfloat16* qrow = qg + (size_t)(grow0 + i) * DH;
        #pragma unroll
        for (int kc = 0; kc < 4; ++kc) {
            U16x8 u; u.u = *(const uint4*)(qrow + kc*32 + g*8);
            aq[kc] = u.s;
        }
    }

    // ---- Phase A: scores for owned key tiles, B-frags straight from global ----
    const int nkt = (wave < 2) ? 3 : 2;
    f32x4 acc[3];
    #pragma unroll
    for (int u = 0; u < 3; ++u) { acc[u][0]=0.f; acc[u][1]=0.f; acc[u][2]=0.f; acc[u][3]=0.f; }
    #pragma unroll
    for (int u = 0; u < 3; ++u) {
        if (u < nkt) {
            int kt = wave + 4*u;
            int key = k0 + kt*16 + i;               // may be OOB: garbage -> masked
            const __hip_bfloat16* krow = kb + (ptrdiff_t)key * DH;
            #pragma unroll
            for (int kc = 0; kc < 4; ++kc) {
                U16x8 u16v; u16v.u = *(const uint4*)(krow + kc*32 + g*8);
                acc[u] = __builtin_amdgcn_mfma_f32_16x16x32_bf16(aq[kc], u16v.s, acc[u], 0, 0, 0);
            }
        }
    }

    // ---- V transpose + LDS writes (loads have had time to land) ----
    vt_xpose_write(VT, vr0, kgp0, dgp0);
    if (two) vt_xpose_write(VT, vr1, kgp1, dgp1);

    // ---- mask + per-wave row max (C layout: col=i=key, row=g*4+r=query) ----
    float sc[3][4], m4[4];
    #pragma unroll
    for (int r = 0; r < 4; ++r) m4[r] = -3e30f;
    #pragma unroll
    for (int u = 0; u < 3; ++u) {
        if (u < nkt) {
            int kt = wave + 4*u;
            int key = k0 + kt*16 + i;
            #pragma unroll
            for (int r = 0; r < 4; ++r) {
                int qrow = s0 + g*4 + r;
                bool valid = (key >= 0) && (key < S_LEN) &&
                             (key >= qrow - half) && (key <= qrow + half);
                float sv = valid ? acc[u][r] * scale : -1e30f;
                sc[u][r] = sv;
                m4[r] = fmaxf(m4[r], sv);
            }
        }
    }
    #pragma unroll
    for (int r = 0; r < 4; ++r) {
        #pragma unroll
        for (int m = 1; m < 16; m <<= 1)
            m4[r] = fmaxf(m4[r], __shfl_xor(m4[r], m, 64));
    }
    if (i == 0) {
        #pragma unroll
        for (int r = 0; r < 4; ++r) pmax[wave][g*4 + r] = m4[r];
    }
    __syncthreads();   // barrier 1: pmax + VT visible

    // ---- softmax: combine max, exp, write P (bf16), partial sums ----
    float M[4], l4[4];
    #pragma unroll
    for (int r = 0; r < 4; ++r) {
        int qr = g*4 + r;
        M[r] = fmaxf(fmaxf(pmax[0][qr], pmax[1][qr]), fmaxf(pmax[2][qr], pmax[3][qr]));
        l4[r] = 0.f;
    }
    #pragma unroll
    for (int u = 0; u < 3; ++u) {
        if (u < nkt) {
            int kt = wave + 4*u;
            #pragma unroll
            for (int r = 0; r < 4; ++r) {
                float p = __expf(sc[u][r] - M[r]);
                l4[r] += p;
                __hip_bfloat16 pb = __float2bfloat16(p);
                Pm[(g*4 + r) * PST + kt*16 + i] = *(unsigned short*)&pb;
            }
        }
    }
    #pragma unroll
    for (int r = 0; r < 4; ++r) {
        #pragma unroll
        for (int m = 1; m < 16; m <<= 1)
            l4[r] += __shfl_xor(l4[r], m, 64);
    }
    if (i == 0) {
        #pragma unroll
        for (int r = 0; r < 4; ++r) psum[wave][g*4 + r] = l4[r];
    }
    __syncthreads();   // barrier 2: P + psum visible

    // ---- Phase B: O = P V for this wave's 32-dim strip ----
    float linv[4];
    #pragma unroll
    for (int r = 0; r < 4; ++r) {
        int qr = g*4 + r;
        linv[r] = 1.0f / (psum[0][qr] + psum[1][qr] + psum[2][qr] + psum[3][qr]);
    }

    short8 ap[5];
    #pragma unroll
    for (int kc = 0; kc < 5; ++kc)
        ap[kc] = *(const short8*)&Pm[i * PST + kc*32 + g*8];

    const int n0 = wave * 32;
    f32x4 oacc[2];
    #pragma unroll
    for (int nt = 0; nt < 2; ++nt) { oacc[nt][0]=0.f; oacc[nt][1]=0.f; oacc[nt][2]=0.f; oacc[nt][3]=0.f; }
    #pragma unroll
    for (int nt = 0; nt < 2; ++nt) {
        int row0 = n0 + nt*16 + i;                 // V^T row = dim
        int dgr = (row0 >> 3) & 7;
        #pragma unroll
        for (int kc = 0; kc < 5; ++kc) {
            int lg = 4*kc + g;
            int sw = lg + dgr; if (sw >= 21) sw -= 21;
            short8 bv = *(const short8*)&VT[row0 * VTS + sw*8];
            oacc[nt] = __builtin_amdgcn_mfma_f32_16x16x32_bf16(ap[kc], bv, oacc[nt], 0, 0, 0);
        }
    }

    // ---- epilogue ----
    #pragma unroll
    for (int nt = 0; nt < 2; ++nt) {
        #pragma unroll
        for (int r = 0; r < 4; ++r) {
            int qrow = s0 + g*4 + r;
            out[((size_t)(b * S_LEN) + qrow) * DH + n0 + nt*16 + i] = oacc[nt][r] * linv[r];
        }
    }
}

extern "C" void kernel_launch(void* const* d_in, const int* in_sizes, int n_in,
                              void* d_out, int out_size, void* d_ws, size_t ws_size,
                              hipStream_t stream) {
    const float* x  = (const float*)d_in[0];
    const float* Wq = (const float*)d_in[1];
    const float* bq = (const float*)d_in[2];
    const float* Wk = (const float*)d_in[3];
    const float* bk = (const float*)d_in[4];
    const float* Wv = (const float*)d_in[5];
    const float* bv = (const float*)d_in[6];
    const int* wsz  = (const int*)d_in[7];

    const int B = 2, S = 4096;
    const int N = B * S;                       // 8192 rows

    __hip_bfloat16* q = (__hip_bfloat16*)d_ws;
    __hip_bfloat16* k = q + (size_t)N * DH;
    __hip_bfloat16* v = k + (size_t)N * DH;
    unsigned short* WT = (unsigned short*)(v + (size_t)N * DH);

    fused_kernel<<<NBLK, 256, 0, stream>>>(x, Wq, bq, Wk, bk, Wv, bv,
                                           q, k, v, WT, (float*)d_out, wsz);
}

// Round 7
// 84.147 us; speedup vs baseline: 3.8576x; 3.8576x over previous
//
#include <hip/hip_runtime.h>
#include <hip/hip_bf16.h>

typedef __attribute__((ext_vector_type(8))) short short8;
typedef __attribute__((ext_vector_type(4))) float f32x4;

union U16x8 { uint4 u; short8 s; unsigned short us[8]; };

#define S_LEN 4096
#define DH    128
#define TQ    16          // queries per attn block
#define VTS   168         // V^T LDS row stride in u16 (21 groups of 8, 336B rows)
#define PST   168         // P LDS row stride in u16
#define XSTR  136         // x-tile LDS stride (bf16 elems)

// ---------------- Kernel 1: QKV projection via MFMA ------------------------
// x split hi/lo bf16 in LDS (2-term MFMA -> fp32-quality x), W gathered
// straight from global fp32 (64 KB/mat, L2-resident after first touch).
// Grid = (256 row-groups) x (3 mats) = 768 blocks = 3 blocks/CU -> 3 waves/SIMD
// of latency hiding. Verified at 85.0 us total (round 2).
__global__ __launch_bounds__(256) void qkv_kernel(
    const float* __restrict__ x,
    const float* __restrict__ Wq, const float* __restrict__ bq,
    const float* __restrict__ Wk, const float* __restrict__ bk,
    const float* __restrict__ Wv, const float* __restrict__ bv,
    __hip_bfloat16* __restrict__ q, __hip_bfloat16* __restrict__ k,
    __hip_bfloat16* __restrict__ v)
{
    __shared__ __align__(16) unsigned short XH[32 * XSTR];
    __shared__ __align__(16) unsigned short XL[32 * XSTR];

    const int t = threadIdx.x;
    const int row0 = blockIdx.x * 32;
    const int mat = blockIdx.y;

    // ---- stage x as hi/lo bf16 (32 rows; same rows for all 3 mats -> L2) ----
    #pragma unroll
    for (int p = 0; p < 4; ++p) {
        int c = t + p * 256;                 // 0..1023
        int r = c >> 5, cg = c & 31;         // row, float4 group
        float4 xv = *(const float4*)(x + (size_t)(row0 + r) * DH + cg * 4);
        unsigned h[2], l[2];
        #pragma unroll
        for (int hw = 0; hw < 2; ++hw) {
            unsigned hh[2], ll[2];
            #pragma unroll
            for (int j = 0; j < 2; ++j) {
                float xs = (&xv.x)[hw * 2 + j];
                __hip_bfloat16 hb = __float2bfloat16(xs);
                float hf = __bfloat162float(hb);
                __hip_bfloat16 lb = __float2bfloat16(xs - hf);
                hh[j] = *(unsigned short*)&hb;
                ll[j] = *(unsigned short*)&lb;
            }
            h[hw] = hh[0] | (hh[1] << 16);
            l[hw] = ll[0] | (ll[1] << 16);
        }
        *(uint2*)&XH[r * XSTR + cg * 4] = make_uint2(h[0], h[1]);
        *(uint2*)&XL[r * XSTR + cg * 4] = make_uint2(l[0], l[1]);
    }
    __syncthreads();

    const int wave = t >> 6, lane = t & 63;
    const int i = lane & 15, g = lane >> 4;

    // ---- A fragments (row m = i, k = kc*32 + g*8 + j) ----
    short8 ah[2][4], al[2][4];
    #pragma unroll
    for (int rt = 0; rt < 2; ++rt)
        #pragma unroll
        for (int kc = 0; kc < 4; ++kc) {
            ah[rt][kc] = *(const short8*)&XH[(rt*16 + i) * XSTR + kc*32 + g*8];
            al[rt][kc] = *(const short8*)&XL[(rt*16 + i) * XSTR + kc*32 + g*8];
        }

    const float* W = (mat == 0) ? Wq : (mat == 1) ? Wk : Wv;
    const float* bias_p = (mat == 0) ? bq : (mat == 1) ? bk : bv;
    __hip_bfloat16* O = (mat == 0) ? q : (mat == 1) ? k : v;

    #pragma unroll
    for (int ct = 0; ct < 2; ++ct) {
        const int col = wave*32 + ct*16 + i;
        const float bias = bias_p[col];

        // B frags: col n = i, k = kc*32 + g*8 + j (strided gather, L2-hot W)
        short8 bf[4];
        #pragma unroll
        for (int kc = 0; kc < 4; ++kc) {
            const float* wp = W + (size_t)(kc*32 + g*8) * DH + col;
            U16x8 u;
            #pragma unroll
            for (int j = 0; j < 8; ++j) {
                __hip_bfloat16 wb = __float2bfloat16(wp[(size_t)j * DH]);
                u.us[j] = *(unsigned short*)&wb;
            }
            bf[kc] = u.s;
        }

        #pragma unroll
        for (int rt = 0; rt < 2; ++rt) {
            f32x4 acc; acc[0]=0.f; acc[1]=0.f; acc[2]=0.f; acc[3]=0.f;
            #pragma unroll
            for (int kc = 0; kc < 4; ++kc) {
                acc = __builtin_amdgcn_mfma_f32_16x16x32_bf16(ah[rt][kc], bf[kc], acc, 0, 0, 0);
                acc = __builtin_amdgcn_mfma_f32_16x16x32_bf16(al[rt][kc], bf[kc], acc, 0, 0, 0);
            }
            #pragma unroll
            for (int r = 0; r < 4; ++r) {
                O[(size_t)(row0 + rt*16 + g*4 + r) * DH + col] =
                    __float2bfloat16(acc[r] + bias);
            }
        }
    }
}

// ---- 8x8 u16 in-register transpose (32 v_perm) + swizzled VT write --------
__device__ inline void vt_xpose_write(unsigned short* VT, const uint4* vr,
                                      int kgp, int dgp)
{
    unsigned w[8][4];   // w[dim][key-pair]
    #pragma unroll
    for (int p = 0; p < 4; ++p) {
        #pragma unroll
        for (int j = 0; j < 4; ++j) {
            unsigned xlo = ((const unsigned*)&vr[2*p])[j];     // key 2p,  dims 2j,2j+1
            unsigned ylo = ((const unsigned*)&vr[2*p+1])[j];   // key 2p+1
            w[2*j][p]   = __builtin_amdgcn_perm(ylo, xlo, 0x05040100u);
            w[2*j+1][p] = __builtin_amdgcn_perm(ylo, xlo, 0x07060302u);
        }
    }
    int sw = kgp + (dgp & 7); if (sw >= 21) sw -= 21;   // bank swizzle, rotate mod 21
    #pragma unroll
    for (int d = 0; d < 8; ++d) {
        int row = dgp*8 + d;
        *(uint4*)&VT[row*VTS + sw*8] =
            make_uint4(w[d][0], w[d][1], w[d][2], w[d][3]);
    }
}

// ---------------- Kernel 2: MFMA sliding-window attention -------------------
// Block = 4 waves, 16 queries, 160-key staged window. Phase A: waves own key
// tiles {w, w+4, w+8}, B-frags gathered straight from global K (cached).
// V transposed into LDS via register 8x8 transpose. Phase B: waves own
// 32-dim strips, P & V^T frags are ds_read_b128.
// Block index is XCD-swizzled (512 % 8 == 0 -> bijective) so each XCD's
// resident q-tiles are contiguous -> K/V window stays L2-resident.
__global__ __launch_bounds__(256) void attn_kernel(
    const __hip_bfloat16* __restrict__ qg,
    const __hip_bfloat16* __restrict__ kg,
    const __hip_bfloat16* __restrict__ vg,
    float* __restrict__ out, const int* __restrict__ wsz)
{
    __shared__ __align__(16) unsigned short VT[128 * VTS];   // 43 KB
    __shared__ __align__(16) unsigned short Pm[TQ * PST];    // 5.25 KB
    __shared__ float pmax[4][16];
    __shared__ float psum[4][16];

    const int t    = threadIdx.x;
    const int wave = t >> 6, lane = t & 63;
    const int i = lane & 15, g = lane >> 4;
    const int bid  = blockIdx.x;
    const int qblk = (bid & 7) * 64 + (bid >> 3);   // XCD swizzle, 512 blocks
    const int b    = qblk >> 8;
    const int s0   = (qblk & 255) * TQ;
    const int k0   = s0 - 64;
    const int half = wsz[0] >> 1;
    const float scale = 0.08838834764831845f;

    const __hip_bfloat16* kb = kg + (size_t)b * S_LEN * DH;
    const __hip_bfloat16* vb = vg + (size_t)b * S_LEN * DH;

    // ---- V tile loads (issued first; 8 keys x 8 dims per tile) ----
    const int kgp0 = t >> 4, dgp0 = t & 15;          // tile t
    const bool two = (t & 3) == 0;
    const int tau2 = 256 + (t >> 2);                 // tiles 256..319
    const int kgp1 = tau2 >> 4, dgp1 = tau2 & 15;
    uint4 vr0[8], vr1[8];
    #pragma unroll
    for (int r = 0; r < 8; ++r) {
        int key = k0 + kgp0*8 + r;
        uint4 val = make_uint4(0u,0u,0u,0u);
        if (key >= 0 && key < S_LEN)
            val = *(const uint4*)(vb + (size_t)key * DH + dgp0*8);
        vr0[r] = val;
    }
    #pragma unroll
    for (int r = 0; r < 8; ++r) {
        int key = k0 + kgp1*8 + r;
        uint4 val = make_uint4(0u,0u,0u,0u);
        if (two && key >= 0 && key < S_LEN)
            val = *(const uint4*)(vb + (size_t)key * DH + dgp1*8);
        vr1[r] = val;
    }

    // ---- Q A-frags from global (same rows for all 4 waves -> L1 broadcast) ----
    short8 aq[4];
    {
        const __hip_bfloat16* qrow = qg + (size_t)(b * S_LEN + s0 + i) * DH;
        #pragma unroll
        for (int kc = 0; kc < 4; ++kc) {
            U16x8 u; u.u = *(const uint4*)(qrow + kc*32 + g*8);
            aq[kc] = u.s;
        }
    }

    // ---- Phase A: scores for owned key tiles, B-frags straight from global ----
    const int nkt = (wave < 2) ? 3 : 2;
    f32x4 acc[3];
    #pragma unroll
    for (int u = 0; u < 3; ++u) { acc[u][0]=0.f; acc[u][1]=0.f; acc[u][2]=0.f; acc[u][3]=0.f; }
    #pragma unroll
    for (int u = 0; u < 3; ++u) {
        if (u < nkt) {
            int kt = wave + 4*u;
            int key = k0 + kt*16 + i;               // may be OOB: garbage -> masked
            const __hip_bfloat16* krow = kb + (ptrdiff_t)key * DH;
            #pragma unroll
            for (int kc = 0; kc < 4; ++kc) {
                U16x8 u16v; u16v.u = *(const uint4*)(krow + kc*32 + g*8);
                acc[u] = __builtin_amdgcn_mfma_f32_16x16x32_bf16(aq[kc], u16v.s, acc[u], 0, 0, 0);
            }
        }
    }

    // ---- V transpose + LDS writes (loads have had time to land) ----
    vt_xpose_write(VT, vr0, kgp0, dgp0);
    if (two) vt_xpose_write(VT, vr1, kgp1, dgp1);

    // ---- mask + per-wave row max (C layout: col=i=key, row=g*4+r=query) ----
    float sc[3][4], m4[4];
    #pragma unroll
    for (int r = 0; r < 4; ++r) m4[r] = -3e30f;
    #pragma unroll
    for (int u = 0; u < 3; ++u) {
        if (u < nkt) {
            int kt = wave + 4*u;
            int key = k0 + kt*16 + i;
            #pragma unroll
            for (int r = 0; r < 4; ++r) {
                int qrow = s0 + g*4 + r;
                bool valid = (key >= 0) && (key < S_LEN) &&
                             (key >= qrow - half) && (key <= qrow + half);
                float sv = valid ? acc[u][r] * scale : -1e30f;
                sc[u][r] = sv;
                m4[r] = fmaxf(m4[r], sv);
            }
        }
    }
    #pragma unroll
    for (int r = 0; r < 4; ++r) {
        #pragma unroll
        for (int m = 1; m < 16; m <<= 1)
            m4[r] = fmaxf(m4[r], __shfl_xor(m4[r], m, 64));
    }
    if (i == 0) {
        #pragma unroll
        for (int r = 0; r < 4; ++r) pmax[wave][g*4 + r] = m4[r];
    }
    __syncthreads();   // barrier 1: pmax + VT visible

    // ---- softmax: combine max, exp, write P (bf16), partial sums ----
    float M[4], l4[4];
    #pragma unroll
    for (int r = 0; r < 4; ++r) {
        int qr = g*4 + r;
        M[r] = fmaxf(fmaxf(pmax[0][qr], pmax[1][qr]), fmaxf(pmax[2][qr], pmax[3][qr]));
        l4[r] = 0.f;
    }
    #pragma unroll
    for (int u = 0; u < 3; ++u) {
        if (u < nkt) {
            int kt = wave + 4*u;
            #pragma unroll
            for (int r = 0; r < 4; ++r) {
                float p = __expf(sc[u][r] - M[r]);
                l4[r] += p;
                __hip_bfloat16 pb = __float2bfloat16(p);
                Pm[(g*4 + r) * PST + kt*16 + i] = *(unsigned short*)&pb;
            }
        }
    }
    #pragma unroll
    for (int r = 0; r < 4; ++r) {
        #pragma unroll
        for (int m = 1; m < 16; m <<= 1)
            l4[r] += __shfl_xor(l4[r], m, 64);
    }
    if (i == 0) {
        #pragma unroll
        for (int r = 0; r < 4; ++r) psum[wave][g*4 + r] = l4[r];
    }
    __syncthreads();   // barrier 2: P + psum visible

    // ---- Phase B: O = P V for this wave's 32-dim strip ----
    float linv[4];
    #pragma unroll
    for (int r = 0; r < 4; ++r) {
        int qr = g*4 + r;
        linv[r] = 1.0f / (psum[0][qr] + psum[1][qr] + psum[2][qr] + psum[3][qr]);
    }

    short8 ap[5];
    #pragma unroll
    for (int kc = 0; kc < 5; ++kc)
        ap[kc] = *(const short8*)&Pm[i * PST + kc*32 + g*8];

    const int n0 = wave * 32;
    f32x4 oacc[2];
    #pragma unroll
    for (int nt = 0; nt < 2; ++nt) { oacc[nt][0]=0.f; oacc[nt][1]=0.f; oacc[nt][2]=0.f; oacc[nt][3]=0.f; }
    #pragma unroll
    for (int nt = 0; nt < 2; ++nt) {
        int row0 = n0 + nt*16 + i;                 // V^T row = dim
        int dgr = (row0 >> 3) & 7;
        #pragma unroll
        for (int kc = 0; kc < 5; ++kc) {
            int lg = 4*kc + g;
            int sw = lg + dgr; if (sw >= 21) sw -= 21;
            short8 bv = *(const short8*)&VT[row0 * VTS + sw*8];
            oacc[nt] = __builtin_amdgcn_mfma_f32_16x16x32_bf16(ap[kc], bv, oacc[nt], 0, 0, 0);
        }
    }

    // ---- epilogue ----
    #pragma unroll
    for (int nt = 0; nt < 2; ++nt) {
        #pragma unroll
        for (int r = 0; r < 4; ++r) {
            int qrow = s0 + g*4 + r;
            out[((size_t)(b * S_LEN) + qrow) * DH + n0 + nt*16 + i] = oacc[nt][r] * linv[r];
        }
    }
}

extern "C" void kernel_launch(void* const* d_in, const int* in_sizes, int n_in,
                              void* d_out, int out_size, void* d_ws, size_t ws_size,
                              hipStream_t stream) {
    const float* x  = (const float*)d_in[0];
    const float* Wq = (const float*)d_in[1];
    const float* bq = (const float*)d_in[2];
    const float* Wk = (const float*)d_in[3];
    const float* bk = (const float*)d_in[4];
    const float* Wv = (const float*)d_in[5];
    const float* bv = (const float*)d_in[6];
    const int* wsz  = (const int*)d_in[7];

    const int B = 2, S = 4096;
    const int N = B * S;                       // 8192 rows

    __hip_bfloat16* q = (__hip_bfloat16*)d_ws;
    __hip_bfloat16* k = q + (size_t)N * DH;
    __hip_bfloat16* v = k + (size_t)N * DH;

    qkv_kernel<<<dim3(256, 3), 256, 0, stream>>>(x, Wq, bq, Wk, bk, Wv, bv, q, k, v);
    attn_kernel<<<N / TQ, 256, 0, stream>>>(q, k, v, (float*)d_out, wsz);
}

// Round 8
// 83.925 us; speedup vs baseline: 3.8678x; 1.0026x over previous
//
#include <hip/hip_runtime.h>
#include <hip/hip_bf16.h>

typedef __attribute__((ext_vector_type(8))) short short8;
typedef __attribute__((ext_vector_type(4))) float f32x4;

union U16x8 { uint4 u; short8 s; unsigned short us[8]; };

#define S_LEN 4096
#define DH    128
#define TQ    32          // queries per attn block (8 waves)
#define VTS   168         // V^T LDS row stride in u16 (21 groups of 8, 336B rows)
#define PST   168         // P LDS row stride in u16
#define XSTR  136         // x-tile LDS stride (bf16 elems)

// ---------------- Kernel 1: QKV projection via MFMA ------------------------
// x split hi/lo bf16 in LDS (2-term MFMA -> fp32-quality x), W gathered
// straight from global fp32 (64 KB/mat, L2-resident after first touch).
// Grid = (256 row-groups) x (3 mats). Verified (round 2/7, 84-85 us total).
__global__ __launch_bounds__(256) void qkv_kernel(
    const float* __restrict__ x,
    const float* __restrict__ Wq, const float* __restrict__ bq,
    const float* __restrict__ Wk, const float* __restrict__ bk,
    const float* __restrict__ Wv, const float* __restrict__ bv,
    __hip_bfloat16* __restrict__ q, __hip_bfloat16* __restrict__ k,
    __hip_bfloat16* __restrict__ v)
{
    __shared__ __align__(16) unsigned short XH[32 * XSTR];
    __shared__ __align__(16) unsigned short XL[32 * XSTR];

    const int t = threadIdx.x;
    const int row0 = blockIdx.x * 32;
    const int mat = blockIdx.y;

    // ---- stage x as hi/lo bf16 (32 rows; same rows for all 3 mats -> L2) ----
    #pragma unroll
    for (int p = 0; p < 4; ++p) {
        int c = t + p * 256;                 // 0..1023
        int r = c >> 5, cg = c & 31;         // row, float4 group
        float4 xv = *(const float4*)(x + (size_t)(row0 + r) * DH + cg * 4);
        unsigned h[2], l[2];
        #pragma unroll
        for (int hw = 0; hw < 2; ++hw) {
            unsigned hh[2], ll[2];
            #pragma unroll
            for (int j = 0; j < 2; ++j) {
                float xs = (&xv.x)[hw * 2 + j];
                __hip_bfloat16 hb = __float2bfloat16(xs);
                float hf = __bfloat162float(hb);
                __hip_bfloat16 lb = __float2bfloat16(xs - hf);
                hh[j] = *(unsigned short*)&hb;
                ll[j] = *(unsigned short*)&lb;
            }
            h[hw] = hh[0] | (hh[1] << 16);
            l[hw] = ll[0] | (ll[1] << 16);
        }
        *(uint2*)&XH[r * XSTR + cg * 4] = make_uint2(h[0], h[1]);
        *(uint2*)&XL[r * XSTR + cg * 4] = make_uint2(l[0], l[1]);
    }
    __syncthreads();

    const int wave = t >> 6, lane = t & 63;
    const int i = lane & 15, g = lane >> 4;

    // ---- A fragments (row m = i, k = kc*32 + g*8 + j) ----
    short8 ah[2][4], al[2][4];
    #pragma unroll
    for (int rt = 0; rt < 2; ++rt)
        #pragma unroll
        for (int kc = 0; kc < 4; ++kc) {
            ah[rt][kc] = *(const short8*)&XH[(rt*16 + i) * XSTR + kc*32 + g*8];
            al[rt][kc] = *(const short8*)&XL[(rt*16 + i) * XSTR + kc*32 + g*8];
        }

    const float* W = (mat == 0) ? Wq : (mat == 1) ? Wk : Wv;
    const float* bias_p = (mat == 0) ? bq : (mat == 1) ? bk : bv;
    __hip_bfloat16* O = (mat == 0) ? q : (mat == 1) ? k : v;

    #pragma unroll
    for (int ct = 0; ct < 2; ++ct) {
        const int col = wave*32 + ct*16 + i;
        const float bias = bias_p[col];

        // B frags: col n = i, k = kc*32 + g*8 + j (strided gather, L2-hot W)
        short8 bf[4];
        #pragma unroll
        for (int kc = 0; kc < 4; ++kc) {
            const float* wp = W + (size_t)(kc*32 + g*8) * DH + col;
            U16x8 u;
            #pragma unroll
            for (int j = 0; j < 8; ++j) {
                __hip_bfloat16 wb = __float2bfloat16(wp[(size_t)j * DH]);
                u.us[j] = *(unsigned short*)&wb;
            }
            bf[kc] = u.s;
        }

        #pragma unroll
        for (int rt = 0; rt < 2; ++rt) {
            f32x4 acc; acc[0]=0.f; acc[1]=0.f; acc[2]=0.f; acc[3]=0.f;
            #pragma unroll
            for (int kc = 0; kc < 4; ++kc) {
                acc = __builtin_amdgcn_mfma_f32_16x16x32_bf16(ah[rt][kc], bf[kc], acc, 0, 0, 0);
                acc = __builtin_amdgcn_mfma_f32_16x16x32_bf16(al[rt][kc], bf[kc], acc, 0, 0, 0);
            }
            #pragma unroll
            for (int r = 0; r < 4; ++r) {
                O[(size_t)(row0 + rt*16 + g*4 + r) * DH + col] =
                    __float2bfloat16(acc[r] + bias);
            }
        }
    }
}

// ---- 8x8 u16 in-register transpose (32 v_perm) + swizzled VT write --------
__device__ inline void vt_xpose_write(unsigned short* VT, const uint4* vr,
                                      int kgp, int dgp)
{
    unsigned w[8][4];   // w[dim][key-pair]
    #pragma unroll
    for (int p = 0; p < 4; ++p) {
        #pragma unroll
        for (int j = 0; j < 4; ++j) {
            unsigned xlo = ((const unsigned*)&vr[2*p])[j];     // key 2p,  dims 2j,2j+1
            unsigned ylo = ((const unsigned*)&vr[2*p+1])[j];   // key 2p+1
            w[2*j][p]   = __builtin_amdgcn_perm(ylo, xlo, 0x05040100u);
            w[2*j+1][p] = __builtin_amdgcn_perm(ylo, xlo, 0x07060302u);
        }
    }
    int sw = kgp + (dgp & 7); if (sw >= 21) sw -= 21;   // bank swizzle, rotate mod 21
    #pragma unroll
    for (int d = 0; d < 8; ++d) {
        int row = dgp*8 + d;
        *(uint4*)&VT[row*VTS + sw*8] =
            make_uint4(w[d][0], w[d][1], w[d][2], w[d][3]);
    }
}

// ---------------- Kernel 2: MFMA sliding-window attention -------------------
// TQ=32: block = 8 waves, 32 queries, SAME 160-key window as TQ=16
// ([s0-64, s0+95]) -> all window-redundant work (V stage+transpose, K/Q
// loads) halves per query; MFMA & softmax totals unchanged (bitwise-same
// per-element math). Wave w: q-tile qt=w>>2; phase A key-tiles
// {wq, wq+4, wq+8} (wq=w&3, nkt=3 for wq<2 else 2); phase B 32-dim strip
// n0=wq*32 of its qt. Grid 256, XCD-swizzled (256%8==0 -> bijective).
__global__ __launch_bounds__(512) void attn_kernel(
    const __hip_bfloat16* __restrict__ qg,
    const __hip_bfloat16* __restrict__ kg,
    const __hip_bfloat16* __restrict__ vg,
    float* __restrict__ out, const int* __restrict__ wsz)
{
    __shared__ __align__(16) unsigned short VT[128 * VTS];   // 43 KB
    __shared__ __align__(16) unsigned short Pm[TQ * PST];    // 10.5 KB
    __shared__ float pmax[8][16];
    __shared__ float psum[8][16];

    const int t    = threadIdx.x;
    const int wave = t >> 6, lane = t & 63;
    const int i = lane & 15, g = lane >> 4;
    const int qt = wave >> 2, wq = wave & 3;
    const int bid  = blockIdx.x;
    const int qblk = (bid & 7) * 32 + (bid >> 3);   // XCD swizzle, 256 blocks
    const int b    = qblk >> 7;
    const int s0   = (qblk & 127) * TQ;
    const int k0   = s0 - 64;
    const int half = wsz[0] >> 1;
    const float scale = 0.08838834764831845f;

    const __hip_bfloat16* kb = kg + (size_t)b * S_LEN * DH;
    const __hip_bfloat16* vb = vg + (size_t)b * S_LEN * DH;

    // ---- V tile loads (one 8-key x 8-dim tile per thread, threads 0..319) ----
    const int kgp0 = t >> 4, dgp0 = t & 15;          // tile t (kgp0 0..19 valid)
    const bool havev = (t < 320);
    uint4 vr0[8];
    if (havev) {
        #pragma unroll
        for (int r = 0; r < 8; ++r) {
            int key = k0 + kgp0*8 + r;
            uint4 val = make_uint4(0u,0u,0u,0u);
            if (key >= 0 && key < S_LEN)
                val = *(const uint4*)(vb + (size_t)key * DH + dgp0*8);
            vr0[r] = val;
        }
    }

    // ---- Q A-frags from global (rows of this wave's q-tile) ----
    short8 aq[4];
    {
        const __hip_bfloat16* qrow = qg + (size_t)(b * S_LEN + s0 + qt*16 + i) * DH;
        #pragma unroll
        for (int kc = 0; kc < 4; ++kc) {
            U16x8 u; u.u = *(const uint4*)(qrow + kc*32 + g*8);
            aq[kc] = u.s;
        }
    }

    // ---- Phase A: scores for owned key tiles, B-frags straight from global ----
    const int nkt = (wq < 2) ? 3 : 2;
    f32x4 acc[3];
    #pragma unroll
    for (int u = 0; u < 3; ++u) { acc[u][0]=0.f; acc[u][1]=0.f; acc[u][2]=0.f; acc[u][3]=0.f; }
    #pragma unroll
    for (int u = 0; u < 3; ++u) {
        if (u < nkt) {
            int kt = wq + 4*u;
            int key = k0 + kt*16 + i;               // may be OOB: garbage -> masked
            const __hip_bfloat16* krow = kb + (ptrdiff_t)key * DH;
            #pragma unroll
            for (int kc = 0; kc < 4; ++kc) {
                U16x8 u16v; u16v.u = *(const uint4*)(krow + kc*32 + g*8);
                acc[u] = __builtin_amdgcn_mfma_f32_16x16x32_bf16(aq[kc], u16v.s, acc[u], 0, 0, 0);
            }
        }
    }

    // ---- V transpose + LDS writes (loads have had time to land) ----
    if (havev) vt_xpose_write(VT, vr0, kgp0, dgp0);

    // ---- mask + per-wave row max (C layout: col=i=key, row=g*4+r=query) ----
    float sc[3][4], m4[4];
    #pragma unroll
    for (int r = 0; r < 4; ++r) m4[r] = -3e30f;
    #pragma unroll
    for (int u = 0; u < 3; ++u) {
        if (u < nkt) {
            int kt = wq + 4*u;
            int key = k0 + kt*16 + i;
            #pragma unroll
            for (int r = 0; r < 4; ++r) {
                int qrow = s0 + qt*16 + g*4 + r;
                bool valid = (key >= 0) && (key < S_LEN) &&
                             (key >= qrow - half) && (key <= qrow + half);
                float sv = valid ? acc[u][r] * scale : -1e30f;
                sc[u][r] = sv;
                m4[r] = fmaxf(m4[r], sv);
            }
        }
    }
    #pragma unroll
    for (int r = 0; r < 4; ++r) {
        #pragma unroll
        for (int m = 1; m < 16; m <<= 1)
            m4[r] = fmaxf(m4[r], __shfl_xor(m4[r], m, 64));
    }
    if (i == 0) {
        #pragma unroll
        for (int r = 0; r < 4; ++r) pmax[wave][g*4 + r] = m4[r];
    }
    __syncthreads();   // barrier 1: pmax + VT visible

    // ---- softmax: combine max (4 waves of this qt), exp, write P, sums ----
    float M[4], l4[4];
    #pragma unroll
    for (int r = 0; r < 4; ++r) {
        int qr = g*4 + r;
        M[r] = fmaxf(fmaxf(pmax[qt*4+0][qr], pmax[qt*4+1][qr]),
                     fmaxf(pmax[qt*4+2][qr], pmax[qt*4+3][qr]));
        l4[r] = 0.f;
    }
    #pragma unroll
    for (int u = 0; u < 3; ++u) {
        if (u < nkt) {
            int kt = wq + 4*u;
            #pragma unroll
            for (int r = 0; r < 4; ++r) {
                float p = __expf(sc[u][r] - M[r]);
                l4[r] += p;
                __hip_bfloat16 pb = __float2bfloat16(p);
                Pm[(qt*16 + g*4 + r) * PST + kt*16 + i] = *(unsigned short*)&pb;
            }
        }
    }
    #pragma unroll
    for (int r = 0; r < 4; ++r) {
        #pragma unroll
        for (int m = 1; m < 16; m <<= 1)
            l4[r] += __shfl_xor(l4[r], m, 64);
    }
    if (i == 0) {
        #pragma unroll
        for (int r = 0; r < 4; ++r) psum[wave][g*4 + r] = l4[r];
    }
    __syncthreads();   // barrier 2: P + psum visible

    // ---- Phase B: O = P V for this wave's (qt, 32-dim strip) ----
    float linv[4];
    #pragma unroll
    for (int r = 0; r < 4; ++r) {
        int qr = g*4 + r;
        linv[r] = 1.0f / (psum[qt*4+0][qr] + psum[qt*4+1][qr] +
                          psum[qt*4+2][qr] + psum[qt*4+3][qr]);
    }

    short8 ap[5];
    #pragma unroll
    for (int kc = 0; kc < 5; ++kc)
        ap[kc] = *(const short8*)&Pm[(qt*16 + i) * PST + kc*32 + g*8];

    const int n0 = wq * 32;
    f32x4 oacc[2];
    #pragma unroll
    for (int nt = 0; nt < 2; ++nt) { oacc[nt][0]=0.f; oacc[nt][1]=0.f; oacc[nt][2]=0.f; oacc[nt][3]=0.f; }
    #pragma unroll
    for (int nt = 0; nt < 2; ++nt) {
        int row0 = n0 + nt*16 + i;                 // V^T row = dim
        int dgr = (row0 >> 3) & 7;
        #pragma unroll
        for (int kc = 0; kc < 5; ++kc) {
            int lg = 4*kc + g;
            int sw = lg + dgr; if (sw >= 21) sw -= 21;
            short8 bv = *(const short8*)&VT[row0 * VTS + sw*8];
            oacc[nt] = __builtin_amdgcn_mfma_f32_16x16x32_bf16(ap[kc], bv, oacc[nt], 0, 0, 0);
        }
    }

    // ---- epilogue ----
    #pragma unroll
    for (int nt = 0; nt < 2; ++nt) {
        #pragma unroll
        for (int r = 0; r < 4; ++r) {
            int qrow = s0 + qt*16 + g*4 + r;
            out[((size_t)(b * S_LEN) + qrow) * DH + n0 + nt*16 + i] = oacc[nt][r] * linv[r];
        }
    }
}

extern "C" void kernel_launch(void* const* d_in, const int* in_sizes, int n_in,
                              void* d_out, int out_size, void* d_ws, size_t ws_size,
                              hipStream_t stream) {
    const float* x  = (const float*)d_in[0];
    const float* Wq = (const float*)d_in[1];
    const float* bq = (const float*)d_in[2];
    const float* Wk = (const float*)d_in[3];
    const float* bk = (const float*)d_in[4];
    const float* Wv = (const float*)d_in[5];
    const float* bv = (const float*)d_in[6];
    const int* wsz  = (const int*)d_in[7];

    const int B = 2, S = 4096;
    const int N = B * S;                       // 8192 rows

    __hip_bfloat16* q = (__hip_bfloat16*)d_ws;
    __hip_bfloat16* k = q + (size_t)N * DH;
    __hip_bfloat16* v = k + (size_t)N * DH;

    qkv_kernel<<<dim3(256, 3), 256, 0, stream>>>(x, Wq, bq, Wk, bk, Wv, bv, q, k, v);
    attn_kernel<<<N / TQ, 512, 0, stream>>>(q, k, v, (float*)d_out, wsz);
}